// Round 14
// baseline (73.623 us; speedup 1.0000x reference)
//
#include <hip/hip_runtime.h>
#include <hip/hip_cooperative_groups.h>
#include <math.h>

namespace cg = cooperative_groups;

#define B 1000
#define D 8
#define PRE 98
#define NEXT 512
#define SC 32
#define ANT 5
#define BM 32
#define NTILE 32          // 32 tiles of 32 rows
#define KP 128            // PRE padded to 128 for MFMA K-steps
#define CSTRIDE 32        // counter padding: 1 counter per 128-B line

// tail-weight LDS layout (floats)
#define OW3 0
#define OW4 3136
#define OWO 7938
#define OB3 8428
#define OB4 8526
#define OBO 8575
#define WTOT 8585

using bf16x8 = __attribute__((ext_vector_type(8))) short;
using f32x4  = __attribute__((ext_vector_type(4))) float;

static __device__ __forceinline__ unsigned short f2bf(float f) {
    union { float f; unsigned u; } v{f};
    unsigned r = (v.u + 0x7fffu + ((v.u >> 16) & 1u)) >> 16;
    return (unsigned short)r;
}

// ---------------------------------------------------------------------------
// k_one — single cooperative kernel, 256 blocks x 512 threads (1 block/CU).
// Phase A (prep, proven numerics from R12/R13's k_prep):
//   blocks 0..127 : sub_wT[d][n][k] = sub_w[d][k][n] (bf16, k zero-pad to 128)
//   blocks 128..135: cut_wT[d][c][k] = gamma*cut_w; gwsum/bwv/coef scalars
//   block 136     : zero padded tile counters
// grid.sync()
// Phase B (main, R9 structure + R12 LN-fold epilogue):
//   stage x (coalesced) -> GEMM1 -> raw h + LN stats from accumulators ->
//   BAR -> GEMM2 on raw h (waves 0-3, LN folded, coherent part stores) ||
//   tail-weight staging (waves 4-7) -> BAR -> counter+spin -> BAR ->
//   tail MLP (waves 0-3, 4 rows/block).
// MFMA 16x16x32 bf16 layouts (m89/m91-verified):
//   A[m][k]: m = lane&15, k = (lane>>4)*8 + j
//   B[k][n]: n = lane&15, k = (lane>>4)*8 + j
//   D[m][n]: n = lane&15, m = (lane>>4)*4 + reg
// ---------------------------------------------------------------------------
__global__ __launch_bounds__(512, 2) void k_one(const float* __restrict__ x,
                                                const float* __restrict__ sub_w,
                                                const float* __restrict__ sub_b,
                                                const float* __restrict__ gamma,
                                                const float* __restrict__ beta,
                                                const float* __restrict__ cut_w,
                                                const float* __restrict__ cut_b,
                                                const float* __restrict__ b_mat,
                                                const float* __restrict__ h_mat,
                                                const float* __restrict__ a_mat,
                                                const int* __restrict__ k_idx,
                                                const float* __restrict__ noise,
                                                const float* __restrict__ clb,
                                                const float* __restrict__ fc3_w,
                                                const float* __restrict__ fc3_b,
                                                const float* __restrict__ fc4_w,
                                                const float* __restrict__ fc4_b,
                                                const float* __restrict__ out_w,
                                                const float* __restrict__ out_b,
                                                unsigned short* __restrict__ sub_wT,
                                                unsigned short* __restrict__ cut_wT,
                                                float* __restrict__ gwsum,
                                                float* __restrict__ bwv,
                                                float* __restrict__ coef,
                                                float* __restrict__ part,
                                                int* __restrict__ counters,
                                                float* __restrict__ out) {
    // Phase A buffers alias phase B's GEMM buffers (dead across grid.sync).
    __shared__ union __align__(16) {
        struct {
            unsigned short tile[32][128];   //  8192 B
            float gs[16][32];               //  2048 B
            float bs[16][32];               //  2048 B
        } pa;
        struct {
            unsigned short x[BM][136];      //  8704 B
            unsigned short h[BM][536];      // 34304 B
        } pb;
    } u;
    __shared__ __align__(16) float st_l[BM][2][8];  // 2048 B
    __shared__ float W_lds[WTOT];                   // 34340 B
    __shared__ float clb_s[SC], am_s[SC * ANT];
    __shared__ float z_s[4][SC];
    __shared__ float z3_s[4][98];
    __shared__ float z4_s[4][49];

    int t = threadIdx.x;
    int bid = blockIdx.x;

    // ================= Phase A: prep =================
    if (bid < 128) {                       // sub_w transpose: (d, n-tile of 32)
        int d = bid >> 4, n0 = (bid & 15) * 32;
        int nn = t & 31, kk = t >> 5;      // kk 0..15
#pragma unroll
        for (int j = 0; j < 8; ++j) {
            int k = j * 16 + kk;
            float v = (k < PRE) ? sub_w[(d * PRE + k) * NEXT + n0 + nn] : 0.f;
            u.pa.tile[nn][k] = f2bf(v);
        }
        __syncthreads();
        int row = t >> 4, c0 = (t & 15) * 8;
        unsigned short* dst = sub_wT + ((size_t)(d * NEXT + n0 + row)) * KP + c0;
        *reinterpret_cast<bf16x8*>(dst) = *reinterpret_cast<bf16x8*>(&u.pa.tile[row][c0]);
    } else if (bid < 136) {                // per-d LN folding
        int d = bid - 128;
        int c = t & 31, ko = t >> 5;       // ko 0..15
        float gs = 0.f, bs = 0.f;
        for (int kk = ko; kk < NEXT; kk += 16) {
            float wv = cut_w[(size_t)(d * NEXT + kk) * SC + c];
            float g  = gamma[d * NEXT + kk];
            float be = beta[d * NEXT + kk];
            cut_wT[(size_t)(d * SC + c) * NEXT + kk] = f2bf(g * wv);
            gs += g * wv;
            bs += be * wv;
        }
        u.pa.gs[ko][c] = gs;
        u.pa.bs[ko][c] = bs;
        __syncthreads();
        if (t < SC) {
            float G = 0.f, Bb = 0.f;
#pragma unroll
            for (int j = 0; j < 16; ++j) { G += u.pa.gs[j][t]; Bb += u.pa.bs[j][t]; }
            gwsum[d * SC + t] = G;
            bwv[d * SC + t] = Bb + cut_b[d * SC + t];
            int kk = k_idx[t];
            float hv = 0.f;
#pragma unroll
            for (int a = 0; a < ANT; ++a)
                hv = fmaf(h_mat[(d * SC + kk) * ANT + a], a_mat[t * ANT + a], hv);
            coef[d * SC + t] = b_mat[d * SC + t] * hv;
        }
    } else if (bid == 136) {               // zero padded tile counters
        if (t < NTILE)
            __hip_atomic_store(&counters[t * CSTRIDE], 0, __ATOMIC_RELAXED,
                               __HIP_MEMORY_SCOPE_AGENT);
    }

    cg::this_grid().sync();   // prep results visible grid-wide

    // ================= Phase B: main =================
    int d = bid >> 5;
    int tile = bid & 31;
    int b0 = tile * BM;
    int w = t >> 6, lane = t & 63;
    int lr = lane >> 4, lc = lane & 15;
    int n0 = w * 64;

    // ---- stage x tile -> bf16 LDS (coalesced), zero rows>=B ----
    for (int idx = t; idx < BM * PRE; idx += 512) {
        int r = idx / PRE, i = idx - r * PRE;
        int b = b0 + r;
        float v = (b < B) ? x[(size_t)b * (D * PRE) + d * PRE + i] : 0.f;
        u.pb.x[r][i] = f2bf(v);
    }
    for (int idx = t; idx < BM * 38; idx += 512) {   // zero k-pad [98,136)
        int r = idx / 38, i = idx - r * 38;
        u.pb.x[r][98 + i] = 0;
    }

    // ---- per-thread scalars ----
    float bias[4];
#pragma unroll
    for (int nf = 0; nf < 4; ++nf) bias[nf] = sub_b[d * NEXT + n0 + nf * 16 + lc];
    float gw_c = 0.f, bw_c = 0.f, cf_c = 0.f;
    if (w < 4) {
        int c = (w & 1) * 16 + lc;
        gw_c = gwsum[d * SC + c];
        bw_c = bwv[d * SC + c];
        cf_c = coef[d * SC + c];
    }
    __syncthreads();   // (0) x ready

    // ---- GEMM1: (32x128)@(128x512); wave -> 32 rows x 64 cols ----
    const unsigned short* bwp = sub_wT + (size_t)d * NEXT * KP + (size_t)(n0 + lc) * KP + lr * 8;
    f32x4 acc[2][4] = {};
#pragma unroll
    for (int ks = 0; ks < 4; ++ks) {
        bf16x8 a0 = *reinterpret_cast<const bf16x8*>(&u.pb.x[lc][ks * 32 + lr * 8]);
        bf16x8 a1 = *reinterpret_cast<const bf16x8*>(&u.pb.x[16 + lc][ks * 32 + lr * 8]);
#pragma unroll
        for (int nf = 0; nf < 4; ++nf) {
            bf16x8 bq = *reinterpret_cast<const bf16x8*>(bwp + (size_t)nf * 16 * KP + ks * 32);
            acc[0][nf] = __builtin_amdgcn_mfma_f32_16x16x32_bf16(a0, bq, acc[0][nf], 0, 0, 0);
            acc[1][nf] = __builtin_amdgcn_mfma_f32_16x16x32_bf16(a1, bq, acc[1][nf], 0, 0, 0);
        }
    }

    // ---- bias+relu -> raw bf16 h + per-row LN stats partials ----
    float s1[2][4] = {}, s2[2][4] = {};
#pragma unroll
    for (int nf = 0; nf < 4; ++nf) {
        int n = n0 + nf * 16 + lc;
#pragma unroll
        for (int mt = 0; mt < 2; ++mt)
#pragma unroll
            for (int r = 0; r < 4; ++r) {
                float hv = fmaxf(acc[mt][nf][r] + bias[nf], 0.f);
                u.pb.h[mt * 16 + lr * 4 + r][n] = f2bf(hv);
                s1[mt][r] += hv;
                s2[mt][r] += hv * hv;
            }
    }
#pragma unroll
    for (int mt = 0; mt < 2; ++mt)
#pragma unroll
        for (int r = 0; r < 4; ++r) {
#pragma unroll
            for (int off = 8; off >= 1; off >>= 1) {
                s1[mt][r] += __shfl_xor(s1[mt][r], off, 16);
                s2[mt][r] += __shfl_xor(s2[mt][r], off, 16);
            }
            if (lc == 0) {
                int row = mt * 16 + lr * 4 + r;
                st_l[row][0][w] = s1[mt][r];
                st_l[row][1][w] = s2[mt][r];
            }
        }
    __syncthreads();   // (1) h + stats complete

    // ---- GEMM2 on raw h (waves 0-3, LN folded) || tail staging (waves 4-7) ----
    if (w < 4) {
        int mt = w >> 1;
        int c = (w & 1) * 16 + lc;
        const unsigned short* cw = cut_wT + (size_t)(d * SC + c) * NEXT + lr * 8;
        f32x4 a2 = {};
#pragma unroll
        for (int ks = 0; ks < 16; ++ks) {
            bf16x8 a = *reinterpret_cast<const bf16x8*>(&u.pb.h[mt * 16 + lc][ks * 32 + lr * 8]);
            bf16x8 g = *reinterpret_cast<const bf16x8*>(cw + ks * 32);
            a2 = __builtin_amdgcn_mfma_f32_16x16x32_bf16(a, g, a2, 0, 0, 0);
        }
#pragma unroll
        for (int r = 0; r < 4; ++r) {
            int m = mt * 16 + lr * 4 + r;
            int b = b0 + m;
            float4 sa = *reinterpret_cast<const float4*>(&st_l[m][0][0]);
            float4 sb = *reinterpret_cast<const float4*>(&st_l[m][0][4]);
            float4 qa = *reinterpret_cast<const float4*>(&st_l[m][1][0]);
            float4 qb = *reinterpret_cast<const float4*>(&st_l[m][1][4]);
            float S1 = (sa.x + sa.y) + (sa.z + sa.w) + (sb.x + sb.y) + (sb.z + sb.w);
            float S2 = (qa.x + qa.y) + (qa.z + qa.w) + (qb.x + qb.y) + (qb.z + qb.w);
            float mu = S1 * (1.f / NEXT);
            float var = S2 * (1.f / NEXT) - mu * mu;
            float rs = rsqrtf(var + 1e-5f);
            float cutv = fmaxf(rs * (a2[r] - mu * gw_c) + bw_c, 0.f) * cf_c;
            if (b < B)
                __hip_atomic_store(&part[((size_t)b * D + d) * SC + c], cutv,
                                   __ATOMIC_RELAXED, __HIP_MEMORY_SCOPE_AGENT);
        }
    } else {
        int tt = t - 256;  // 0..255
        for (int i = tt; i < 3136; i += 256) W_lds[OW3 + i] = fc3_w[i];
        for (int i = tt; i < 4802; i += 256) W_lds[OW4 + i] = fc4_w[i];
        for (int i = tt; i < 490; i += 256)  W_lds[OWO + i] = out_w[i];
        if (tt < 98) W_lds[OB3 + tt] = fc3_b[tt];
        if (tt < 49) W_lds[OB4 + tt] = fc4_b[tt];
        if (tt < 10) W_lds[OBO + tt] = out_b[tt];
        if (tt >= 128 && tt < 128 + SC) clb_s[tt - 128] = clb[tt - 128];
        if (tt >= 160 && tt < 160 + SC * ANT) am_s[tt - 160] = a_mat[tt - 160];
    }

    // ---- per-tile sync: relaxed RMW + spin on padded private line ----
    __syncthreads();   // (2) drains coherent part stores (vmcnt) + W_lds
    if (t == 0) {
        __hip_atomic_fetch_add(&counters[tile * CSTRIDE], 1,
                               __ATOMIC_RELAXED, __HIP_MEMORY_SCOPE_AGENT);
        while (__hip_atomic_load(&counters[tile * CSTRIDE],
                                 __ATOMIC_RELAXED, __HIP_MEMORY_SCOPE_AGENT) < D)
            __builtin_amdgcn_s_sleep(2);
    }
    __syncthreads();   // (3)

    // ---- tail MLP: this block handles rows d*4 .. d*4+3; wave w<4 -> one row ----
    if (w < 4) {
        int b = b0 + d * 4 + w;
        if (b < B) {
            int c = lane & 31, dg = lane >> 5;   // dg in {0,1}
            float s = 0.f;
#pragma unroll
            for (int i = 0; i < 4; ++i)
                s += __hip_atomic_load(&part[((size_t)b * D + (dg + 2 * i)) * SC + c],
                                       __ATOMIC_RELAXED, __HIP_MEMORY_SCOPE_AGENT);
            s += __shfl_xor(s, 32);
            if (lane < 32) {
                float zz = s + clb_s[c];
#pragma unroll
                for (int a = 0; a < ANT; ++a)
                    zz = fmaf(noise[((size_t)b * SC + c) * ANT + a], am_s[c * ANT + a], zz);
                z_s[w][c] = fmaxf(zz, 0.f);
            }
            for (int o = lane; o < 98; o += 64) {
                float s3 = W_lds[OB3 + o];
#pragma unroll
                for (int j = 0; j < SC; ++j) s3 = fmaf(z_s[w][j], W_lds[OW3 + j * 98 + o], s3);
                z3_s[w][o] = fmaxf(s3, 0.f);
            }
            if (lane < 49) {
                float s4 = W_lds[OB4 + lane];
                for (int j = 0; j < 98; ++j) s4 = fmaf(z3_s[w][j], W_lds[OW4 + j * 49 + lane], s4);
                z4_s[w][lane] = fmaxf(s4, 0.f);
            }
            float v = -INFINITY;
            if (lane < 10) {
                float so = W_lds[OBO + lane];
                for (int j = 0; j < 49; ++j) so = fmaf(z4_s[w][j], W_lds[OWO + j * 10 + lane], so);
                v = so;
            }
            float mx = v;
#pragma unroll
            for (int off = 8; off >= 1; off >>= 1) mx = fmaxf(mx, __shfl_xor(mx, off, 16));
            float e = (lane < 10) ? expf(v - mx) : 0.f;
            float ssum = e;
#pragma unroll
            for (int off = 8; off >= 1; off >>= 1) ssum += __shfl_xor(ssum, off, 16);
            if (lane < 10) out[b * 10 + lane] = v - mx - logf(ssum);
        }
    }
}

// ---------------------------------------------------------------------------
extern "C" void kernel_launch(void* const* d_in, const int* in_sizes, int n_in,
                              void* d_out, int out_size, void* d_ws, size_t ws_size,
                              hipStream_t stream) {
    const float* x      = (const float*)d_in[0];
    const float* noise  = (const float*)d_in[1];
    const float* sub_w  = (const float*)d_in[2];
    const float* sub_b  = (const float*)d_in[3];
    const float* ln_g   = (const float*)d_in[4];
    const float* ln_b   = (const float*)d_in[5];
    const float* cut_w  = (const float*)d_in[6];
    const float* cut_b  = (const float*)d_in[7];
    const float* b_mat  = (const float*)d_in[8];
    const float* h_mat  = (const float*)d_in[9];
    const float* a_mat  = (const float*)d_in[10];
    const float* clb    = (const float*)d_in[11];
    const float* fc3_w  = (const float*)d_in[12];
    const float* fc3_b  = (const float*)d_in[13];
    const float* fc4_w  = (const float*)d_in[14];
    const float* fc4_b  = (const float*)d_in[15];
    const float* out_w  = (const float*)d_in[16];
    const float* out_b  = (const float*)d_in[17];
    const int*   k_idx  = (const int*)d_in[18];
    float* out = (float*)d_out;

    char* ws = (char*)d_ws;
    float* part            = (float*)ws;                          // 1,024,000 B [b][d][c]
    unsigned short* sub_wT = (unsigned short*)(ws + (1 << 20));   // 1,048,576 B
    unsigned short* cut_wT = (unsigned short*)(ws + (2 << 20));   //   262,144 B
    float* gwsum           = (float*)(ws + (2 << 20) + 262144);   //     1,024 B
    float* bwv             = (float*)(ws + (2 << 20) + 263168);   //     1,024 B
    float* coef            = (float*)(ws + (2 << 20) + 264192);   //     1,024 B
    int* counters          = (int*)(ws + (2 << 20) + 266240);     //     4,096 B

    void* args[] = {
        (void*)&x, (void*)&sub_w, (void*)&sub_b, (void*)&ln_g, (void*)&ln_b,
        (void*)&cut_w, (void*)&cut_b, (void*)&b_mat, (void*)&h_mat,
        (void*)&a_mat, (void*)&k_idx, (void*)&noise, (void*)&clb,
        (void*)&fc3_w, (void*)&fc3_b, (void*)&fc4_w, (void*)&fc4_b,
        (void*)&out_w, (void*)&out_b, (void*)&sub_wT, (void*)&cut_wT,
        (void*)&gwsum, (void*)&bwv, (void*)&coef, (void*)&part,
        (void*)&counters, (void*)&out
    };
    hipLaunchCooperativeKernel((void*)k_one, dim3(D * NTILE), dim3(512),
                               args, 0, stream);
}

// Round 15
// 41.476 us; speedup vs baseline: 1.7751x; 1.7751x over previous
//
#include <hip/hip_runtime.h>
#include <math.h>

#define B 1000
#define D 8
#define PRE 98
#define NEXT 512
#define SC 32
#define ANT 5
#define BM 32
#define NTILE 32          // 32 tiles of 32 rows
#define KP 128            // PRE padded to 128 for MFMA K-steps
#define CSTRIDE 32        // counter padding: 1 counter per 128-B line

// tail-weight LDS layout (floats)
#define OW3 0
#define OW4 3136
#define OWO 7938
#define OB3 8428
#define OB4 8526
#define OBO 8575
#define WTOT 8585

using bf16x8 = __attribute__((ext_vector_type(8))) short;
using f32x4  = __attribute__((ext_vector_type(4))) float;

static __device__ __forceinline__ unsigned short f2bf(float f) {
    union { float f; unsigned u; } v{f};
    unsigned r = (v.u + 0x7fffu + ((v.u >> 16) & 1u)) >> 16;
    return (unsigned short)r;
}

// ---------------------------------------------------------------------------
// Prep (136 blocks) — R12/R13-proven numerics:
//  blocks 0..127 : sub_wT[d][n][k] (bf16, k zero-padded to 128) = sub_w[d][k][n]
//  blocks 128..135 (one per d): LN-folded GEMM2 weights + scalars:
//    cut_wT[d][c][k] = gamma[d][k] * cut_w[d][k][c]   (bf16)
//    gwsum[d][c] = sum_k gamma*cut_w ;  bwv[d][c] = sum_k beta*cut_w + cut_b
//    coef[d][c]  = b_mat * sum_a h_mat[d][k_idx[c]][a] * a_mat[c][a]
//  block 0 also zeroes the padded tile counters.
// ---------------------------------------------------------------------------
__global__ __launch_bounds__(256) void k_prep(const float* __restrict__ sub_w,
                                              const float* __restrict__ cut_w,
                                              const float* __restrict__ gamma,
                                              const float* __restrict__ beta,
                                              const float* __restrict__ cut_b,
                                              const float* __restrict__ b_mat,
                                              const float* __restrict__ h_mat,
                                              const float* __restrict__ a_mat,
                                              const int* __restrict__ k_idx,
                                              unsigned short* __restrict__ sub_wT,
                                              unsigned short* __restrict__ cut_wT,
                                              float* __restrict__ gwsum,
                                              float* __restrict__ bwv,
                                              float* __restrict__ coef,
                                              int* __restrict__ counters) {
    __shared__ __align__(16) unsigned short tile[32][128];
    __shared__ float gs_l[8][32], bs_l[8][32];
    int t = threadIdx.x, bid = blockIdx.x;
    if (bid == 0 && t < NTILE)
        __hip_atomic_store(&counters[t * CSTRIDE], 0, __ATOMIC_RELAXED,
                           __HIP_MEMORY_SCOPE_AGENT);
    if (bid < 128) {                       // sub_w: (d, n-tile of 32), k = 0..127
        int d = bid >> 4, n0 = (bid & 15) * 32;
        int nn = t & 31, kk = t >> 5;      // kk 0..7
#pragma unroll
        for (int j = 0; j < 16; ++j) {
            int k = j * 8 + kk;
            float v = (k < PRE) ? sub_w[(d * PRE + k) * NEXT + n0 + nn] : 0.f;
            tile[nn][k] = f2bf(v);
        }
        __syncthreads();
        int row = t >> 3, c0 = (t & 7) * 16;
        unsigned short* dst = sub_wT + ((size_t)(d * NEXT + n0 + row)) * KP + c0;
        *reinterpret_cast<bf16x8*>(dst)     = *reinterpret_cast<bf16x8*>(&tile[row][c0]);
        *reinterpret_cast<bf16x8*>(dst + 8) = *reinterpret_cast<bf16x8*>(&tile[row][c0 + 8]);
    } else {                               // per-d LN folding
        int d = bid - 128;
        int c = t & 31, ko = t >> 5;       // ko 0..7
        float gs = 0.f, bs = 0.f;
        for (int kk = ko; kk < NEXT; kk += 8) {
            float wv = cut_w[(size_t)(d * NEXT + kk) * SC + c];
            float g  = gamma[d * NEXT + kk];
            float be = beta[d * NEXT + kk];
            cut_wT[(size_t)(d * SC + c) * NEXT + kk] = f2bf(g * wv);
            gs += g * wv;
            bs += be * wv;
        }
        gs_l[ko][c] = gs;
        bs_l[ko][c] = bs;
        __syncthreads();
        if (t < SC) {
            float G = 0.f, Bb = 0.f;
#pragma unroll
            for (int j = 0; j < 8; ++j) { G += gs_l[j][t]; Bb += bs_l[j][t]; }
            gwsum[d * SC + t] = G;
            bwv[d * SC + t] = Bb + cut_b[d * SC + t];
            int kk = k_idx[t];
            float hv = 0.f;
#pragma unroll
            for (int a = 0; a < ANT; ++a)
                hv = fmaf(h_mat[(d * SC + kk) * ANT + a], a_mat[t * ANT + a], hv);
            coef[d * SC + t] = b_mat[d * SC + t] * hv;
        }
    }
}

// ---------------------------------------------------------------------------
// k_all (256 blocks = (d, 32-row tile), 512 thr = 8 waves) — R9 structure
// with two phases deleted:
//   A-frags DIRECT from x (float4, no x_lds, no stage barrier) ->
//   GEMM1 -> raw bf16 h + LN stats from accumulators -> BAR(1) ->
//   GEMM2 on raw h (waves 0-3, LN folded into weights/epilogue, coherent
//   part stores) || tail-weight staging (waves 4-7) -> BAR(2) ->
//   counter+spin -> BAR(3) -> tail MLP (waves 0-3, 4 rows/block).
// MFMA 16x16x32 bf16 layouts (m89/m91-verified):
//   A[m][k]: m = lane&15, k = (lane>>4)*8 + j
//   B[k][n]: n = lane&15, k = (lane>>4)*8 + j
//   D[m][n]: n = lane&15, m = (lane>>4)*4 + reg
// ---------------------------------------------------------------------------
__global__ __launch_bounds__(512) void k_all(const float* __restrict__ x,
                                             const unsigned short* __restrict__ sub_wT,
                                             const float* __restrict__ sub_b,
                                             const unsigned short* __restrict__ cut_wT,
                                             const float* __restrict__ gwsum,
                                             const float* __restrict__ bwv,
                                             const float* __restrict__ coef,
                                             const float* __restrict__ noise,
                                             const float* __restrict__ clb,
                                             const float* __restrict__ a_mat,
                                             const float* __restrict__ fc3_w,
                                             const float* __restrict__ fc3_b,
                                             const float* __restrict__ fc4_w,
                                             const float* __restrict__ fc4_b,
                                             const float* __restrict__ out_w,
                                             const float* __restrict__ out_b,
                                             float* __restrict__ part,
                                             int* __restrict__ counters,
                                             float* __restrict__ out) {
    __shared__ __align__(16) unsigned short h_lds[BM][536];   // 34304 B
    __shared__ __align__(16) float st_l[BM][2][8];            //  2048 B
    __shared__ float W_lds[WTOT];                             // 34340 B
    __shared__ float clb_s[SC], am_s[SC * ANT];
    __shared__ float z_s[4][SC];
    __shared__ float z3_s[4][98];
    __shared__ float z4_s[4][49];

    int t = threadIdx.x;
    int d = blockIdx.x >> 5;
    int tile = blockIdx.x & 31;
    int b0 = tile * BM;
    int w = t >> 6, lane = t & 63;
    int lr = lane >> 4, lc = lane & 15;
    int n0 = w * 64;

    // ---- A fragments DIRECT from x: per lane, frag ks covers k = ks*32+lr*8..+7
    // = 32 contiguous bytes (two float4). k>=98 is zero-pad; only frag ks=3,
    // lr=0 straddles the boundary (k=96..103 -> 2 valid) -> float2 + zeros.
    bf16x8 af[2][4];
#pragma unroll
    for (int mt = 0; mt < 2; ++mt) {
        int row = b0 + mt * 16 + lc;
        bool ok = row < B;
        const float* xr = x + (size_t)(ok ? row : 0) * (D * PRE) + d * PRE;
#pragma unroll
        for (int ks = 0; ks < 4; ++ks) {
            int k0 = ks * 32 + lr * 8;
            bf16x8 v;
            if (!ok || k0 >= PRE) {
                v = bf16x8{0, 0, 0, 0, 0, 0, 0, 0};
            } else if (k0 + 8 <= 96) {        // fully in-range (k<96<=PRE-2)
                float4 p0 = *reinterpret_cast<const float4*>(xr + k0);
                float4 p1 = *reinterpret_cast<const float4*>(xr + k0 + 4);
                v[0] = (short)f2bf(p0.x); v[1] = (short)f2bf(p0.y);
                v[2] = (short)f2bf(p0.z); v[3] = (short)f2bf(p0.w);
                v[4] = (short)f2bf(p1.x); v[5] = (short)f2bf(p1.y);
                v[6] = (short)f2bf(p1.z); v[7] = (short)f2bf(p1.w);
            } else {                           // k0 == 96: two valid values
                float2 p = *reinterpret_cast<const float2*>(xr + 96);
                v = bf16x8{(short)f2bf(p.x), (short)f2bf(p.y), 0, 0, 0, 0, 0, 0};
            }
            af[mt][ks] = v;
        }
    }

    // ---- per-thread scalars (issued early, independent) ----
    float bias[4];
#pragma unroll
    for (int nf = 0; nf < 4; ++nf) bias[nf] = sub_b[d * NEXT + n0 + nf * 16 + lc];
    float gw_c = 0.f, bw_c = 0.f, cf_c = 0.f;
    if (w < 4) {
        int c = (w & 1) * 16 + lc;
        gw_c = gwsum[d * SC + c];
        bw_c = bwv[d * SC + c];
        cf_c = coef[d * SC + c];
    }

    // ---- GEMM1: (32x128)@(128x512); wave -> 32 rows x 64 cols ----
    const unsigned short* bwp = sub_wT + (size_t)d * NEXT * KP + (size_t)(n0 + lc) * KP + lr * 8;
    f32x4 acc[2][4] = {};
#pragma unroll
    for (int ks = 0; ks < 4; ++ks)
#pragma unroll
        for (int nf = 0; nf < 4; ++nf) {
            bf16x8 bq = *reinterpret_cast<const bf16x8*>(bwp + (size_t)nf * 16 * KP + ks * 32);
            acc[0][nf] = __builtin_amdgcn_mfma_f32_16x16x32_bf16(af[0][ks], bq, acc[0][nf], 0, 0, 0);
            acc[1][nf] = __builtin_amdgcn_mfma_f32_16x16x32_bf16(af[1][ks], bq, acc[1][nf], 0, 0, 0);
        }

    // ---- bias+relu -> raw bf16 h + per-row LN stats partials (R12-proven) ----
    float s1[2][4] = {}, s2[2][4] = {};
#pragma unroll
    for (int nf = 0; nf < 4; ++nf) {
        int n = n0 + nf * 16 + lc;
#pragma unroll
        for (int mt = 0; mt < 2; ++mt)
#pragma unroll
            for (int r = 0; r < 4; ++r) {
                float hv = fmaxf(acc[mt][nf][r] + bias[nf], 0.f);
                h_lds[mt * 16 + lr * 4 + r][n] = f2bf(hv);
                s1[mt][r] += hv;
                s2[mt][r] += hv * hv;
            }
    }
#pragma unroll
    for (int mt = 0; mt < 2; ++mt)
#pragma unroll
        for (int r = 0; r < 4; ++r) {
#pragma unroll
            for (int off = 8; off >= 1; off >>= 1) {
                s1[mt][r] += __shfl_xor(s1[mt][r], off, 16);
                s2[mt][r] += __shfl_xor(s2[mt][r], off, 16);
            }
            if (lc == 0) {
                int row = mt * 16 + lr * 4 + r;
                st_l[row][0][w] = s1[mt][r];
                st_l[row][1][w] = s2[mt][r];
            }
        }
    __syncthreads();   // (1) h + stats complete

    // ---- GEMM2 on raw h (waves 0-3, LN folded) || tail staging (waves 4-7) ----
    if (w < 4) {
        int mt = w >> 1;
        int c = (w & 1) * 16 + lc;
        const unsigned short* cw = cut_wT + (size_t)(d * SC + c) * NEXT + lr * 8;
        f32x4 a2 = {};
#pragma unroll
        for (int ks = 0; ks < 16; ++ks) {
            bf16x8 a = *reinterpret_cast<const bf16x8*>(&h_lds[mt * 16 + lc][ks * 32 + lr * 8]);
            bf16x8 g = *reinterpret_cast<const bf16x8*>(cw + ks * 32);
            a2 = __builtin_amdgcn_mfma_f32_16x16x32_bf16(a, g, a2, 0, 0, 0);
        }
#pragma unroll
        for (int r = 0; r < 4; ++r) {
            int m = mt * 16 + lr * 4 + r;
            int b = b0 + m;
            float4 sa = *reinterpret_cast<const float4*>(&st_l[m][0][0]);
            float4 sb = *reinterpret_cast<const float4*>(&st_l[m][0][4]);
            float4 qa = *reinterpret_cast<const float4*>(&st_l[m][1][0]);
            float4 qb = *reinterpret_cast<const float4*>(&st_l[m][1][4]);
            float S1 = (sa.x + sa.y) + (sa.z + sa.w) + (sb.x + sb.y) + (sb.z + sb.w);
            float S2 = (qa.x + qa.y) + (qa.z + qa.w) + (qb.x + qb.y) + (qb.z + qb.w);
            float mu = S1 * (1.f / NEXT);
            float var = S2 * (1.f / NEXT) - mu * mu;
            float rs = rsqrtf(var + 1e-5f);
            float cutv = fmaxf(rs * (a2[r] - mu * gw_c) + bw_c, 0.f) * cf_c;
            if (b < B)
                __hip_atomic_store(&part[((size_t)b * D + d) * SC + c], cutv,
                                   __ATOMIC_RELAXED, __HIP_MEMORY_SCOPE_AGENT);
        }
    } else {
        int tt = t - 256;  // 0..255
        for (int i = tt; i < 3136; i += 256) W_lds[OW3 + i] = fc3_w[i];
        for (int i = tt; i < 4802; i += 256) W_lds[OW4 + i] = fc4_w[i];
        for (int i = tt; i < 490; i += 256)  W_lds[OWO + i] = out_w[i];
        if (tt < 98) W_lds[OB3 + tt] = fc3_b[tt];
        if (tt < 49) W_lds[OB4 + tt] = fc4_b[tt];
        if (tt < 10) W_lds[OBO + tt] = out_b[tt];
        if (tt >= 128 && tt < 128 + SC) clb_s[tt - 128] = clb[tt - 128];
        if (tt >= 160 && tt < 160 + SC * ANT) am_s[tt - 160] = a_mat[tt - 160];
    }

    // ---- per-tile sync: relaxed RMW + spin on padded private line (R9) ----
    __syncthreads();   // (2) drains coherent part stores (vmcnt) + W_lds
    if (t == 0) {
        __hip_atomic_fetch_add(&counters[tile * CSTRIDE], 1,
                               __ATOMIC_RELAXED, __HIP_MEMORY_SCOPE_AGENT);
        while (__hip_atomic_load(&counters[tile * CSTRIDE],
                                 __ATOMIC_RELAXED, __HIP_MEMORY_SCOPE_AGENT) < D)
            __builtin_amdgcn_s_sleep(2);
    }
    __syncthreads();   // (3)

    // ---- tail MLP: this block handles rows d*4 .. d*4+3; wave w<4 -> one row ----
    if (w < 4) {
        int b = b0 + d * 4 + w;
        if (b < B) {
            int c = lane & 31, dg = lane >> 5;   // dg in {0,1}
            float s = 0.f;
#pragma unroll
            for (int i = 0; i < 4; ++i)
                s += __hip_atomic_load(&part[((size_t)b * D + (dg + 2 * i)) * SC + c],
                                       __ATOMIC_RELAXED, __HIP_MEMORY_SCOPE_AGENT);
            s += __shfl_xor(s, 32);
            if (lane < 32) {
                float zz = s + clb_s[c];
#pragma unroll
                for (int a = 0; a < ANT; ++a)
                    zz = fmaf(noise[(b * SC + c) * ANT + a], am_s[c * ANT + a], zz);
                z_s[w][c] = fmaxf(zz, 0.f);
            }
            for (int o = lane; o < 98; o += 64) {
                float s3 = W_lds[OB3 + o];
#pragma unroll
                for (int j = 0; j < SC; ++j) s3 = fmaf(z_s[w][j], W_lds[OW3 + j * 98 + o], s3);
                z3_s[w][o] = fmaxf(s3, 0.f);
            }
            if (lane < 49) {
                float s4 = W_lds[OB4 + lane];
                for (int j = 0; j < 98; ++j) s4 = fmaf(z3_s[w][j], W_lds[OW4 + j * 49 + lane], s4);
                z4_s[w][lane] = fmaxf(s4, 0.f);
            }
            float v = -INFINITY;
            if (lane < 10) {
                float so = W_lds[OBO + lane];
                for (int j = 0; j < 49; ++j) so = fmaf(z4_s[w][j], W_lds[OWO + j * 10 + lane], so);
                v = so;
            }
            float mx = v;
#pragma unroll
            for (int off = 8; off >= 1; off >>= 1) mx = fmaxf(mx, __shfl_xor(mx, off, 16));
            float e = (lane < 10) ? expf(v - mx) : 0.f;
            float ssum = e;
#pragma unroll
            for (int off = 8; off >= 1; off >>= 1) ssum += __shfl_xor(ssum, off, 16);
            if (lane < 10) out[b * 10 + lane] = v - mx - logf(ssum);
        }
    }
}

// ---------------------------------------------------------------------------
extern "C" void kernel_launch(void* const* d_in, const int* in_sizes, int n_in,
                              void* d_out, int out_size, void* d_ws, size_t ws_size,
                              hipStream_t stream) {
    const float* x      = (const float*)d_in[0];
    const float* noise  = (const float*)d_in[1];
    const float* sub_w  = (const float*)d_in[2];
    const float* sub_b  = (const float*)d_in[3];
    const float* ln_g   = (const float*)d_in[4];
    const float* ln_b   = (const float*)d_in[5];
    const float* cut_w  = (const float*)d_in[6];
    const float* cut_b  = (const float*)d_in[7];
    const float* b_mat  = (const float*)d_in[8];
    const float* h_mat  = (const float*)d_in[9];
    const float* a_mat  = (const float*)d_in[10];
    const float* clb    = (const float*)d_in[11];
    const float* fc3_w  = (const float*)d_in[12];
    const float* fc3_b  = (const float*)d_in[13];
    const float* fc4_w  = (const float*)d_in[14];
    const float* fc4_b  = (const float*)d_in[15];
    const float* out_w  = (const float*)d_in[16];
    const float* out_b  = (const float*)d_in[17];
    const int*   k_idx  = (const int*)d_in[18];
    float* out = (float*)d_out;

    char* ws = (char*)d_ws;
    float* part            = (float*)ws;                          // 1,024,000 B [b][d][c]
    unsigned short* sub_wT = (unsigned short*)(ws + (1 << 20));   // 1,048,576 B
    unsigned short* cut_wT = (unsigned short*)(ws + (2 << 20));   //   262,144 B
    float* gwsum           = (float*)(ws + (2 << 20) + 262144);   //     1,024 B
    float* bwv             = (float*)(ws + (2 << 20) + 263168);   //     1,024 B
    float* coef            = (float*)(ws + (2 << 20) + 264192);   //     1,024 B
    int* counters          = (int*)(ws + (2 << 20) + 266240);     //     4,096 B

    k_prep<<<136, 256, 0, stream>>>(sub_w, cut_w, ln_g, ln_b, cut_b, b_mat,
                                    h_mat, a_mat, k_idx, sub_wT, cut_wT,
                                    gwsum, bwv, coef, counters);
    k_all<<<D * NTILE, 512, 0, stream>>>(x, sub_wT, sub_b, cut_wT, gwsum, bwv,
                                         coef, noise, clb, a_mat, fc3_w, fc3_b,
                                         fc4_w, fc4_b, out_w, out_b, part,
                                         counters, out);
}

// Round 16
// 41.466 us; speedup vs baseline: 1.7755x; 1.0002x over previous
//
#include <hip/hip_runtime.h>
#include <math.h>

#define B 1000
#define D 8
#define PRE 98
#define NEXT 512
#define SC 32
#define ANT 5
#define BM 32
#define NTILE 32          // 32 tiles of 32 rows
#define KP 128            // PRE padded to 128 for MFMA K-steps
#define CSTRIDE 32        // counter padding: 1 counter per 128-B line

// tail-weight LDS layout (floats)
#define OW3 0
#define OW4 3136
#define OWO 7938
#define OB3 8428
#define OB4 8526
#define OBO 8575
#define WTOT 8585

using bf16x8 = __attribute__((ext_vector_type(8))) short;
using f32x4  = __attribute__((ext_vector_type(4))) float;

static __device__ __forceinline__ unsigned short f2bf(float f) {
    union { float f; unsigned u; } v{f};
    unsigned r = (v.u + 0x7fffu + ((v.u >> 16) & 1u)) >> 16;
    return (unsigned short)r;
}

// ---------------------------------------------------------------------------
// Prep (136 blocks) — R12/R13/R15-proven numerics:
//  blocks 0..127 : sub_wT[d][n][k] (bf16, k zero-padded to 128) = sub_w[d][k][n]
//  blocks 128..135 (one per d): LN-folded GEMM2 weights + scalars:
//    cut_wT[d][c][k] = gamma[d][k] * cut_w[d][k][c]   (bf16)
//    gwsum[d][c] = sum_k gamma*cut_w ;  bwv[d][c] = sum_k beta*cut_w + cut_b
//    coef[d][c]  = b_mat * sum_a h_mat[d][k_idx[c]][a] * a_mat[c][a]
//  block 0 also zeroes the padded tile counters.
// ---------------------------------------------------------------------------
__global__ __launch_bounds__(256) void k_prep(const float* __restrict__ sub_w,
                                              const float* __restrict__ cut_w,
                                              const float* __restrict__ gamma,
                                              const float* __restrict__ beta,
                                              const float* __restrict__ cut_b,
                                              const float* __restrict__ b_mat,
                                              const float* __restrict__ h_mat,
                                              const float* __restrict__ a_mat,
                                              const int* __restrict__ k_idx,
                                              unsigned short* __restrict__ sub_wT,
                                              unsigned short* __restrict__ cut_wT,
                                              float* __restrict__ gwsum,
                                              float* __restrict__ bwv,
                                              float* __restrict__ coef,
                                              int* __restrict__ counters) {
    __shared__ __align__(16) unsigned short tile[32][128];
    __shared__ float gs_l[8][32], bs_l[8][32];
    int t = threadIdx.x, bid = blockIdx.x;
    if (bid == 0 && t < NTILE)
        __hip_atomic_store(&counters[t * CSTRIDE], 0, __ATOMIC_RELAXED,
                           __HIP_MEMORY_SCOPE_AGENT);
    if (bid < 128) {                       // sub_w: (d, n-tile of 32), k = 0..127
        int d = bid >> 4, n0 = (bid & 15) * 32;
        int nn = t & 31, kk = t >> 5;      // kk 0..7
#pragma unroll
        for (int j = 0; j < 16; ++j) {
            int k = j * 8 + kk;
            float v = (k < PRE) ? sub_w[(d * PRE + k) * NEXT + n0 + nn] : 0.f;
            tile[nn][k] = f2bf(v);
        }
        __syncthreads();
        int row = t >> 3, c0 = (t & 7) * 16;
        unsigned short* dst = sub_wT + ((size_t)(d * NEXT + n0 + row)) * KP + c0;
        *reinterpret_cast<bf16x8*>(dst)     = *reinterpret_cast<bf16x8*>(&tile[row][c0]);
        *reinterpret_cast<bf16x8*>(dst + 8) = *reinterpret_cast<bf16x8*>(&tile[row][c0 + 8]);
    } else {                               // per-d LN folding
        int d = bid - 128;
        int c = t & 31, ko = t >> 5;       // ko 0..7
        float gs = 0.f, bs = 0.f;
        for (int kk = ko; kk < NEXT; kk += 8) {
            float wv = cut_w[(size_t)(d * NEXT + kk) * SC + c];
            float g  = gamma[d * NEXT + kk];
            float be = beta[d * NEXT + kk];
            cut_wT[(size_t)(d * SC + c) * NEXT + kk] = f2bf(g * wv);
            gs += g * wv;
            bs += be * wv;
        }
        gs_l[ko][c] = gs;
        bs_l[ko][c] = bs;
        __syncthreads();
        if (t < SC) {
            float G = 0.f, Bb = 0.f;
#pragma unroll
            for (int j = 0; j < 8; ++j) { G += gs_l[j][t]; Bb += bs_l[j][t]; }
            gwsum[d * SC + t] = G;
            bwv[d * SC + t] = Bb + cut_b[d * SC + t];
            int kk = k_idx[t];
            float hv = 0.f;
#pragma unroll
            for (int a = 0; a < ANT; ++a)
                hv = fmaf(h_mat[(d * SC + kk) * ANT + a], a_mat[t * ANT + a], hv);
            coef[d * SC + t] = b_mat[d * SC + t] * hv;
        }
    }
}

// ---------------------------------------------------------------------------
// k_all (256 blocks = (d, 32-row tile), 512 thr = 8 waves) — R9 structure
// (coalesced x_lds stage kept!) with ONE change: the LayerNorm pass and its
// barrier are deleted; stats come from GEMM1 accumulators, LN is folded into
// GEMM2 weights (prep) + epilogue.
//   issue bq -> stage x (coalesced) -> BAR(0) -> GEMM1 ->
//   gq/param issue -> bias+relu -> raw h + stats -> BAR(1) ->
//   GEMM2 (waves 0-3, folded epilogue, coherent part stores) ||
//   tail staging (waves 4-7) -> BAR(2) -> counter+spin -> BAR(3) -> tail MLP.
// MFMA 16x16x32 bf16 layouts (m89/m91-verified):
//   A[m][k]: m = lane&15, k = (lane>>4)*8 + j
//   B[k][n]: n = lane&15, k = (lane>>4)*8 + j
//   D[m][n]: n = lane&15, m = (lane>>4)*4 + reg
// ---------------------------------------------------------------------------
__global__ __launch_bounds__(512) void k_all(const float* __restrict__ x,
                                             const unsigned short* __restrict__ sub_wT,
                                             const float* __restrict__ sub_b,
                                             const unsigned short* __restrict__ cut_wT,
                                             const float* __restrict__ gwsum,
                                             const float* __restrict__ bwv,
                                             const float* __restrict__ coef,
                                             const float* __restrict__ noise,
                                             const float* __restrict__ clb,
                                             const float* __restrict__ a_mat,
                                             const float* __restrict__ fc3_w,
                                             const float* __restrict__ fc3_b,
                                             const float* __restrict__ fc4_w,
                                             const float* __restrict__ fc4_b,
                                             const float* __restrict__ out_w,
                                             const float* __restrict__ out_b,
                                             float* __restrict__ part,
                                             int* __restrict__ counters,
                                             float* __restrict__ out) {
    __shared__ __align__(16) unsigned short x_lds[BM][136];   //  8704 B
    __shared__ __align__(16) unsigned short h_lds[BM][536];   // 34304 B
    __shared__ __align__(16) float st_l[BM][2][8];            //  2048 B
    __shared__ float W_lds[WTOT];                             // 34340 B
    __shared__ float clb_s[SC], am_s[SC * ANT];
    __shared__ float z_s[4][SC];
    __shared__ float z3_s[4][98];
    __shared__ float z4_s[4][49];

    int t = threadIdx.x;
    int d = blockIdx.x >> 5;
    int tile = blockIdx.x & 31;
    int b0 = tile * BM;
    int w = t >> 6, lane = t & 63;
    int lr = lane >> 4, lc = lane & 15;
    int n0 = w * 64;

    // ---- issue GEMM1 B-fragment loads (latency hides under x-stage) ----
    const unsigned short* bwp = sub_wT + (size_t)d * NEXT * KP + (size_t)(n0 + lc) * KP + lr * 8;
    bf16x8 bq[4][4];
#pragma unroll
    for (int ks = 0; ks < 4; ++ks)
#pragma unroll
        for (int nf = 0; nf < 4; ++nf)
            bq[ks][nf] = *reinterpret_cast<const bf16x8*>(bwp + (size_t)nf * 16 * KP + ks * 32);

    // ---- stage x tile -> bf16 LDS (coalesced, R9-proven) ----
    for (int idx = t; idx < BM * 136; idx += 512) {
        int r = idx / 136, i = idx - r * 136;
        int b = b0 + r;
        float v = (b < B && i < PRE) ? x[b * (D * PRE) + d * PRE + i] : 0.f;
        x_lds[r][i] = f2bf(v);
    }
    __syncthreads();   // (0) x ready

    // ---- GEMM1: (32x128)@(128x512); wave -> 32 rows x 64 cols ----
    f32x4 acc[2][4] = {};
#pragma unroll
    for (int ks = 0; ks < 4; ++ks) {
        bf16x8 a0 = *reinterpret_cast<const bf16x8*>(&x_lds[lc][ks * 32 + lr * 8]);
        bf16x8 a1 = *reinterpret_cast<const bf16x8*>(&x_lds[16 + lc][ks * 32 + lr * 8]);
#pragma unroll
        for (int nf = 0; nf < 4; ++nf) {
            acc[0][nf] = __builtin_amdgcn_mfma_f32_16x16x32_bf16(a0, bq[ks][nf], acc[0][nf], 0, 0, 0);
            acc[1][nf] = __builtin_amdgcn_mfma_f32_16x16x32_bf16(a1, bq[ks][nf], acc[1][nf], 0, 0, 0);
        }
    }

    // ---- issue GEMM2 B-frags + folded params (hide under h-write) ----
    bf16x8 gq[16];
    float gw_c = 0.f, bw_c = 0.f, cf_c = 0.f;
    if (w < 4) {
        int c = (w & 1) * 16 + lc;
        const unsigned short* cw = cut_wT + (size_t)(d * SC + c) * NEXT + lr * 8;
#pragma unroll
        for (int ks = 0; ks < 16; ++ks)
            gq[ks] = *reinterpret_cast<const bf16x8*>(cw + ks * 32);
        gw_c = gwsum[d * SC + c];
        bw_c = bwv[d * SC + c];
        cf_c = coef[d * SC + c];
    }

    // ---- bias+relu -> raw bf16 h + per-row LN stats partials ----
    {
        const float* sb = sub_b + d * NEXT;
        float s1[2][4] = {}, s2[2][4] = {};
#pragma unroll
        for (int nf = 0; nf < 4; ++nf) {
            int n = n0 + nf * 16 + lc;
            float bias = sb[n];
#pragma unroll
            for (int mt = 0; mt < 2; ++mt)
#pragma unroll
                for (int r = 0; r < 4; ++r) {
                    float hv = fmaxf(acc[mt][nf][r] + bias, 0.f);
                    h_lds[mt * 16 + lr * 4 + r][n] = f2bf(hv);
                    s1[mt][r] += hv;
                    s2[mt][r] += hv * hv;
                }
        }
#pragma unroll
        for (int mt = 0; mt < 2; ++mt)
#pragma unroll
            for (int r = 0; r < 4; ++r) {
#pragma unroll
                for (int off = 8; off >= 1; off >>= 1) {
                    s1[mt][r] += __shfl_xor(s1[mt][r], off, 16);
                    s2[mt][r] += __shfl_xor(s2[mt][r], off, 16);
                }
                if (lc == 0) {
                    int row = mt * 16 + lr * 4 + r;
                    st_l[row][0][w] = s1[mt][r];
                    st_l[row][1][w] = s2[mt][r];
                }
            }
    }
    __syncthreads();   // (1) h + stats complete (LN pass deleted)

    // ---- GEMM2 on raw h (waves 0-3, folded epilogue) || tail staging ----
    if (w < 4) {
        int mt = w >> 1;
        int c = (w & 1) * 16 + lc;
        f32x4 a2 = {};
#pragma unroll
        for (int ks = 0; ks < 16; ++ks) {
            bf16x8 a = *reinterpret_cast<const bf16x8*>(&h_lds[mt * 16 + lc][ks * 32 + lr * 8]);
            a2 = __builtin_amdgcn_mfma_f32_16x16x32_bf16(a, gq[ks], a2, 0, 0, 0);
        }
#pragma unroll
        for (int r = 0; r < 4; ++r) {
            int m = mt * 16 + lr * 4 + r;
            int b = b0 + m;
            float4 sa = *reinterpret_cast<const float4*>(&st_l[m][0][0]);
            float4 sb = *reinterpret_cast<const float4*>(&st_l[m][0][4]);
            float4 qa = *reinterpret_cast<const float4*>(&st_l[m][1][0]);
            float4 qb = *reinterpret_cast<const float4*>(&st_l[m][1][4]);
            float S1 = (sa.x + sa.y) + (sa.z + sa.w) + (sb.x + sb.y) + (sb.z + sb.w);
            float S2 = (qa.x + qa.y) + (qa.z + qa.w) + (qb.x + qb.y) + (qb.z + qb.w);
            float mu = S1 * (1.f / NEXT);
            float var = S2 * (1.f / NEXT) - mu * mu;
            float rs = rsqrtf(var + 1e-5f);
            float cutv = fmaxf(rs * (a2[r] - mu * gw_c) + bw_c, 0.f) * cf_c;
            if (b < B)
                __hip_atomic_store(&part[((size_t)b * D + d) * SC + c], cutv,
                                   __ATOMIC_RELAXED, __HIP_MEMORY_SCOPE_AGENT);
        }
    } else {
        int tt = t - 256;  // 0..255
        for (int i = tt; i < 3136; i += 256) W_lds[OW3 + i] = fc3_w[i];
        for (int i = tt; i < 4802; i += 256) W_lds[OW4 + i] = fc4_w[i];
        for (int i = tt; i < 490; i += 256)  W_lds[OWO + i] = out_w[i];
        if (tt < 98) W_lds[OB3 + tt] = fc3_b[tt];
        if (tt < 49) W_lds[OB4 + tt] = fc4_b[tt];
        if (tt < 10) W_lds[OBO + tt] = out_b[tt];
        if (tt >= 128 && tt < 128 + SC) clb_s[tt - 128] = clb[tt - 128];
        if (tt >= 160 && tt < 160 + SC * ANT) am_s[tt - 160] = a_mat[tt - 160];
    }

    // ---- per-tile sync: relaxed RMW + spin on padded private line (R9) ----
    __syncthreads();   // (2) drains coherent part stores (vmcnt) + W_lds
    if (t == 0) {
        __hip_atomic_fetch_add(&counters[tile * CSTRIDE], 1,
                               __ATOMIC_RELAXED, __HIP_MEMORY_SCOPE_AGENT);
        while (__hip_atomic_load(&counters[tile * CSTRIDE],
                                 __ATOMIC_RELAXED, __HIP_MEMORY_SCOPE_AGENT) < D)
            __builtin_amdgcn_s_sleep(2);
    }
    __syncthreads();   // (3)

    // ---- tail MLP: this block handles rows d*4 .. d*4+3; wave w<4 -> one row ----
    if (w < 4) {
        int b = b0 + d * 4 + w;
        if (b < B) {
            int c = lane & 31, dg = lane >> 5;   // dg in {0,1}
            float s = 0.f;
#pragma unroll
            for (int i = 0; i < 4; ++i)
                s += __hip_atomic_load(&part[((size_t)b * D + (dg + 2 * i)) * SC + c],
                                       __ATOMIC_RELAXED, __HIP_MEMORY_SCOPE_AGENT);
            s += __shfl_xor(s, 32);
            if (lane < 32) {
                float zz = s + clb_s[c];
#pragma unroll
                for (int a = 0; a < ANT; ++a)
                    zz = fmaf(noise[(b * SC + c) * ANT + a], am_s[c * ANT + a], zz);
                z_s[w][c] = fmaxf(zz, 0.f);
            }
            for (int o = lane; o < 98; o += 64) {
                float s3 = W_lds[OB3 + o];
#pragma unroll
                for (int j = 0; j < SC; ++j) s3 = fmaf(z_s[w][j], W_lds[OW3 + j * 98 + o], s3);
                z3_s[w][o] = fmaxf(s3, 0.f);
            }
            if (lane < 49) {
                float s4 = W_lds[OB4 + lane];
                for (int j = 0; j < 98; ++j) s4 = fmaf(z3_s[w][j], W_lds[OW4 + j * 49 + lane], s4);
                z4_s[w][lane] = fmaxf(s4, 0.f);
            }
            float v = -INFINITY;
            if (lane < 10) {
                float so = W_lds[OBO + lane];
                for (int j = 0; j < 49; ++j) so = fmaf(z4_s[w][j], W_lds[OWO + j * 10 + lane], so);
                v = so;
            }
            float mx = v;
#pragma unroll
            for (int off = 8; off >= 1; off >>= 1) mx = fmaxf(mx, __shfl_xor(mx, off, 16));
            float e = (lane < 10) ? expf(v - mx) : 0.f;
            float ssum = e;
#pragma unroll
            for (int off = 8; off >= 1; off >>= 1) ssum += __shfl_xor(ssum, off, 16);
            if (lane < 10) out[b * 10 + lane] = v - mx - logf(ssum);
        }
    }
}

// ---------------------------------------------------------------------------
extern "C" void kernel_launch(void* const* d_in, const int* in_sizes, int n_in,
                              void* d_out, int out_size, void* d_ws, size_t ws_size,
                              hipStream_t stream) {
    const float* x      = (const float*)d_in[0];
    const float* noise  = (const float*)d_in[1];
    const float* sub_w  = (const float*)d_in[2];
    const float* sub_b  = (const float*)d_in[3];
    const float* ln_g   = (const float*)d_in[4];
    const float* ln_b   = (const float*)d_in[5];
    const float* cut_w  = (const float*)d_in[6];
    const float* cut_b  = (const float*)d_in[7];
    const float* b_mat  = (const float*)d_in[8];
    const float* h_mat  = (const float*)d_in[9];
    const float* a_mat  = (const float*)d_in[10];
    const float* clb    = (const float*)d_in[11];
    const float* fc3_w  = (const float*)d_in[12];
    const float* fc3_b  = (const float*)d_in[13];
    const float* fc4_w  = (const float*)d_in[14];
    const float* fc4_b  = (const float*)d_in[15];
    const float* out_w  = (const float*)d_in[16];
    const float* out_b  = (const float*)d_in[17];
    const int*   k_idx  = (const int*)d_in[18];
    float* out = (float*)d_out;

    char* ws = (char*)d_ws;
    float* part            = (float*)ws;                          // 1,024,000 B [b][d][c]
    unsigned short* sub_wT = (unsigned short*)(ws + (1 << 20));   // 1,048,576 B
    unsigned short* cut_wT = (unsigned short*)(ws + (2 << 20));   //   262,144 B
    float* gwsum           = (float*)(ws + (2 << 20) + 262144);   //     1,024 B
    float* bwv             = (float*)(ws + (2 << 20) + 263168);   //     1,024 B
    float* coef            = (float*)(ws + (2 << 20) + 264192);   //     1,024 B
    int* counters          = (int*)(ws + (2 << 20) + 266240);     //     4,096 B

    k_prep<<<136, 256, 0, stream>>>(sub_w, cut_w, ln_g, ln_b, cut_b, b_mat,
                                    h_mat, a_mat, k_idx, sub_wT, cut_wT,
                                    gwsum, bwv, coef, counters);
    k_all<<<D * NTILE, 512, 0, stream>>>(x, sub_wT, sub_b, cut_wT, gwsum, bwv,
                                         coef, noise, clb, a_mat, fc3_w, fc3_b,
                                         fc4_w, fc4_b, out_w, out_b, part,
                                         counters, out);
}

// Round 17
// 28.096 us; speedup vs baseline: 2.6204x; 1.4759x over previous
//
#include <hip/hip_runtime.h>
#include <math.h>

#define B 1000
#define D 8
#define PRE 98
#define NEXT 512
#define SC 32
#define ANT 5
#define BM 32
#define NTILE 32          // 32 tiles of 32 rows
#define KP 128            // PRE padded to 128 for MFMA K-steps
#define CSTRIDE 32        // counter padding: 1 counter per 128-B line

// tail-weight LDS layout (floats)
#define OW3 0
#define OW4 3136
#define OWO 7938
#define OB3 8428
#define OB4 8526
#define OBO 8575
#define WTOT 8585

using bf16x8 = __attribute__((ext_vector_type(8))) short;
using f32x4  = __attribute__((ext_vector_type(4))) float;

static __device__ __forceinline__ unsigned short f2bf(float f) {
    union { float f; unsigned u; } v{f};
    unsigned r = (v.u + 0x7fffu + ((v.u >> 16) & 1u)) >> 16;
    return (unsigned short)r;
}

// ---------------------------------------------------------------------------
// Prep (160 blocks — R9's PROVEN coalesced shape, gamma-fold fused):
//  blocks 0..127 : sub_wT[d][n][k] (bf16, k zero-padded to 128) = sub_w[d][k][n]
//  blocks 128..159 (d, k-chunk of 128): cut_wT[d][c][k] = gamma[d][k]*cut_w[d][k][c]
//    via LDS transpose (coalesced bf16x8 stores), plus per-chunk partial sums:
//    gw_part[d][chunk][c] = sum_k g*wv ; bw_part[d][chunk][c] = sum_k be*wv
//    (+cut_b folded into chunk 0). coef computed by chunk-0 blocks.
//  block 0 zeroes the padded tile counters.
// ---------------------------------------------------------------------------
__global__ __launch_bounds__(256) void k_prep(const float* __restrict__ sub_w,
                                              const float* __restrict__ cut_w,
                                              const float* __restrict__ gamma,
                                              const float* __restrict__ beta,
                                              const float* __restrict__ cut_b,
                                              const float* __restrict__ b_mat,
                                              const float* __restrict__ h_mat,
                                              const float* __restrict__ a_mat,
                                              const int* __restrict__ k_idx,
                                              unsigned short* __restrict__ sub_wT,
                                              unsigned short* __restrict__ cut_wT,
                                              float* __restrict__ gw_part,
                                              float* __restrict__ bw_part,
                                              float* __restrict__ coef,
                                              int* __restrict__ counters) {
    __shared__ __align__(16) unsigned short tile[32][128];
    __shared__ float gs_l[8][32], bs_l[8][32];
    int t = threadIdx.x, bid = blockIdx.x;
    if (bid == 0 && t < NTILE)
        __hip_atomic_store(&counters[t * CSTRIDE], 0, __ATOMIC_RELAXED,
                           __HIP_MEMORY_SCOPE_AGENT);
    if (bid < 128) {                       // sub_w: (d, n-tile of 32), k = 0..127
        int d = bid >> 4, n0 = (bid & 15) * 32;
        int nn = t & 31, kk = t >> 5;      // kk 0..7
#pragma unroll
        for (int j = 0; j < 16; ++j) {
            int k = j * 8 + kk;
            float v = (k < PRE) ? sub_w[(d * PRE + k) * NEXT + n0 + nn] : 0.f;
            tile[nn][k] = f2bf(v);
        }
        __syncthreads();
        int row = t >> 3, c0 = (t & 7) * 16;
        unsigned short* dst = sub_wT + ((size_t)(d * NEXT + n0 + row)) * KP + c0;
        *reinterpret_cast<bf16x8*>(dst)     = *reinterpret_cast<bf16x8*>(&tile[row][c0]);
        *reinterpret_cast<bf16x8*>(dst + 8) = *reinterpret_cast<bf16x8*>(&tile[row][c0 + 8]);
    } else {                               // cut_w: (d, k-chunk of 128), gamma-folded
        int bb = bid - 128;                // 0..31
        int d = bb >> 2, chunk = bb & 3, k0 = chunk * 128;
        int nn = t & 31, kk = t >> 5;
        float gs = 0.f, bs = 0.f;
#pragma unroll
        for (int j = 0; j < 16; ++j) {
            int kl = j * 8 + kk;
            int k = k0 + kl;
            float wv = cut_w[(size_t)(d * NEXT + k) * SC + nn];
            float g  = gamma[d * NEXT + k];
            float be = beta[d * NEXT + k];
            tile[nn][kl] = f2bf(g * wv);
            gs += g * wv;
            bs += be * wv;
        }
        gs_l[kk][nn] = gs;
        bs_l[kk][nn] = bs;
        __syncthreads();
        int row = t >> 3, c0 = (t & 7) * 16;
        unsigned short* dst = cut_wT + ((size_t)(d * SC + row)) * NEXT + k0 + c0;
        *reinterpret_cast<bf16x8*>(dst)     = *reinterpret_cast<bf16x8*>(&tile[row][c0]);
        *reinterpret_cast<bf16x8*>(dst + 8) = *reinterpret_cast<bf16x8*>(&tile[row][c0 + 8]);
        if (t < SC) {
            float G = 0.f, Bb = 0.f;
#pragma unroll
            for (int j = 0; j < 8; ++j) { G += gs_l[j][t]; Bb += bs_l[j][t]; }
            gw_part[(d * 4 + chunk) * SC + t] = G;
            float extra = (chunk == 0) ? cut_b[d * SC + t] : 0.f;
            bw_part[(d * 4 + chunk) * SC + t] = Bb + extra;
            if (chunk == 0) {
                int kk2 = k_idx[t];
                float hv = 0.f;
#pragma unroll
                for (int a = 0; a < ANT; ++a)
                    hv = fmaf(h_mat[(d * SC + kk2) * ANT + a], a_mat[t * ANT + a], hv);
                coef[d * SC + t] = b_mat[d * SC + t] * hv;
            }
        }
    }
}

// ---------------------------------------------------------------------------
// k_all (256 blocks = (d, 32-row tile), 512 thr = 8 waves) — R16's body
// (R9 structure + LN-fold, coalesced x-stage) with partial-sum param loads.
//   issue bq -> stage x (coalesced) -> BAR(0) -> GEMM1 ->
//   gq/param issue -> bias+relu -> raw h + stats -> BAR(1) ->
//   GEMM2 (waves 0-3, folded epilogue, coherent part stores) ||
//   tail staging (waves 4-7) -> BAR(2) -> counter+spin -> BAR(3) -> tail MLP.
// MFMA 16x16x32 bf16 layouts (m89/m91-verified):
//   A[m][k]: m = lane&15, k = (lane>>4)*8 + j
//   B[k][n]: n = lane&15, k = (lane>>4)*8 + j
//   D[m][n]: n = lane&15, m = (lane>>4)*4 + reg
// ---------------------------------------------------------------------------
__global__ __launch_bounds__(512) void k_all(const float* __restrict__ x,
                                             const unsigned short* __restrict__ sub_wT,
                                             const float* __restrict__ sub_b,
                                             const unsigned short* __restrict__ cut_wT,
                                             const float* __restrict__ gw_part,
                                             const float* __restrict__ bw_part,
                                             const float* __restrict__ coef,
                                             const float* __restrict__ noise,
                                             const float* __restrict__ clb,
                                             const float* __restrict__ a_mat,
                                             const float* __restrict__ fc3_w,
                                             const float* __restrict__ fc3_b,
                                             const float* __restrict__ fc4_w,
                                             const float* __restrict__ fc4_b,
                                             const float* __restrict__ out_w,
                                             const float* __restrict__ out_b,
                                             float* __restrict__ part,
                                             int* __restrict__ counters,
                                             float* __restrict__ out) {
    __shared__ __align__(16) unsigned short x_lds[BM][136];   //  8704 B
    __shared__ __align__(16) unsigned short h_lds[BM][536];   // 34304 B
    __shared__ __align__(16) float st_l[BM][2][8];            //  2048 B
    __shared__ float W_lds[WTOT];                             // 34340 B
    __shared__ float clb_s[SC], am_s[SC * ANT];
    __shared__ float z_s[4][SC];
    __shared__ float z3_s[4][98];
    __shared__ float z4_s[4][49];

    int t = threadIdx.x;
    int d = blockIdx.x >> 5;
    int tile = blockIdx.x & 31;
    int b0 = tile * BM;
    int w = t >> 6, lane = t & 63;
    int lr = lane >> 4, lc = lane & 15;
    int n0 = w * 64;

    // ---- issue GEMM1 B-fragment loads (latency hides under x-stage) ----
    const unsigned short* bwp = sub_wT + (size_t)d * NEXT * KP + (size_t)(n0 + lc) * KP + lr * 8;
    bf16x8 bq[4][4];
#pragma unroll
    for (int ks = 0; ks < 4; ++ks)
#pragma unroll
        for (int nf = 0; nf < 4; ++nf)
            bq[ks][nf] = *reinterpret_cast<const bf16x8*>(bwp + (size_t)nf * 16 * KP + ks * 32);

    // ---- stage x tile -> bf16 LDS (coalesced, R9-proven) ----
    for (int idx = t; idx < BM * 136; idx += 512) {
        int r = idx / 136, i = idx - r * 136;
        int b = b0 + r;
        float v = (b < B && i < PRE) ? x[b * (D * PRE) + d * PRE + i] : 0.f;
        x_lds[r][i] = f2bf(v);
    }
    __syncthreads();   // (0) x ready

    // ---- GEMM1: (32x128)@(128x512); wave -> 32 rows x 64 cols ----
    f32x4 acc[2][4] = {};
#pragma unroll
    for (int ks = 0; ks < 4; ++ks) {
        bf16x8 a0 = *reinterpret_cast<const bf16x8*>(&x_lds[lc][ks * 32 + lr * 8]);
        bf16x8 a1 = *reinterpret_cast<const bf16x8*>(&x_lds[16 + lc][ks * 32 + lr * 8]);
#pragma unroll
        for (int nf = 0; nf < 4; ++nf) {
            acc[0][nf] = __builtin_amdgcn_mfma_f32_16x16x32_bf16(a0, bq[ks][nf], acc[0][nf], 0, 0, 0);
            acc[1][nf] = __builtin_amdgcn_mfma_f32_16x16x32_bf16(a1, bq[ks][nf], acc[1][nf], 0, 0, 0);
        }
    }

    // ---- issue GEMM2 B-frags + folded params (hide under h-write) ----
    bf16x8 gq[16];
    float gw_c = 0.f, bw_c = 0.f, cf_c = 0.f;
    if (w < 4) {
        int c = (w & 1) * 16 + lc;
        const unsigned short* cw = cut_wT + (size_t)(d * SC + c) * NEXT + lr * 8;
#pragma unroll
        for (int ks = 0; ks < 16; ++ks)
            gq[ks] = *reinterpret_cast<const bf16x8*>(cw + ks * 32);
        const float* gp = gw_part + (d * 4) * SC + c;
        const float* bp = bw_part + (d * 4) * SC + c;
        gw_c = (gp[0] + gp[SC]) + (gp[2 * SC] + gp[3 * SC]);
        bw_c = (bp[0] + bp[SC]) + (bp[2 * SC] + bp[3 * SC]);
        cf_c = coef[d * SC + c];
    }

    // ---- bias+relu -> raw bf16 h + per-row LN stats partials ----
    {
        const float* sb = sub_b + d * NEXT;
        float s1[2][4] = {}, s2[2][4] = {};
#pragma unroll
        for (int nf = 0; nf < 4; ++nf) {
            int n = n0 + nf * 16 + lc;
            float bias = sb[n];
#pragma unroll
            for (int mt = 0; mt < 2; ++mt)
#pragma unroll
                for (int r = 0; r < 4; ++r) {
                    float hv = fmaxf(acc[mt][nf][r] + bias, 0.f);
                    h_lds[mt * 16 + lr * 4 + r][n] = f2bf(hv);
                    s1[mt][r] += hv;
                    s2[mt][r] += hv * hv;
                }
        }
#pragma unroll
        for (int mt = 0; mt < 2; ++mt)
#pragma unroll
            for (int r = 0; r < 4; ++r) {
#pragma unroll
                for (int off = 8; off >= 1; off >>= 1) {
                    s1[mt][r] += __shfl_xor(s1[mt][r], off, 16);
                    s2[mt][r] += __shfl_xor(s2[mt][r], off, 16);
                }
                if (lc == 0) {
                    int row = mt * 16 + lr * 4 + r;
                    st_l[row][0][w] = s1[mt][r];
                    st_l[row][1][w] = s2[mt][r];
                }
            }
    }
    __syncthreads();   // (1) h + stats complete (LN pass deleted)

    // ---- GEMM2 on raw h (waves 0-3, folded epilogue) || tail staging ----
    if (w < 4) {
        int mt = w >> 1;
        int c = (w & 1) * 16 + lc;
        f32x4 a2 = {};
#pragma unroll
        for (int ks = 0; ks < 16; ++ks) {
            bf16x8 a = *reinterpret_cast<const bf16x8*>(&h_lds[mt * 16 + lc][ks * 32 + lr * 8]);
            a2 = __builtin_amdgcn_mfma_f32_16x16x32_bf16(a, gq[ks], a2, 0, 0, 0);
        }
#pragma unroll
        for (int r = 0; r < 4; ++r) {
            int m = mt * 16 + lr * 4 + r;
            int b = b0 + m;
            float4 sa = *reinterpret_cast<const float4*>(&st_l[m][0][0]);
            float4 sb = *reinterpret_cast<const float4*>(&st_l[m][0][4]);
            float4 qa = *reinterpret_cast<const float4*>(&st_l[m][1][0]);
            float4 qb = *reinterpret_cast<const float4*>(&st_l[m][1][4]);
            float S1 = (sa.x + sa.y) + (sa.z + sa.w) + (sb.x + sb.y) + (sb.z + sb.w);
            float S2 = (qa.x + qa.y) + (qa.z + qa.w) + (qb.x + qb.y) + (qb.z + qb.w);
            float mu = S1 * (1.f / NEXT);
            float var = S2 * (1.f / NEXT) - mu * mu;
            float rs = rsqrtf(var + 1e-5f);
            float cutv = fmaxf(rs * (a2[r] - mu * gw_c) + bw_c, 0.f) * cf_c;
            if (b < B)
                __hip_atomic_store(&part[((size_t)b * D + d) * SC + c], cutv,
                                   __ATOMIC_RELAXED, __HIP_MEMORY_SCOPE_AGENT);
        }
    } else {
        int tt = t - 256;  // 0..255
        for (int i = tt; i < 3136; i += 256) W_lds[OW3 + i] = fc3_w[i];
        for (int i = tt; i < 4802; i += 256) W_lds[OW4 + i] = fc4_w[i];
        for (int i = tt; i < 490; i += 256)  W_lds[OWO + i] = out_w[i];
        if (tt < 98) W_lds[OB3 + tt] = fc3_b[tt];
        if (tt < 49) W_lds[OB4 + tt] = fc4_b[tt];
        if (tt < 10) W_lds[OBO + tt] = out_b[tt];
        if (tt >= 128 && tt < 128 + SC) clb_s[tt - 128] = clb[tt - 128];
        if (tt >= 160 && tt < 160 + SC * ANT) am_s[tt - 160] = a_mat[tt - 160];
    }

    // ---- per-tile sync: relaxed RMW + spin on padded private line (R9) ----
    __syncthreads();   // (2) drains coherent part stores (vmcnt) + W_lds
    if (t == 0) {
        __hip_atomic_fetch_add(&counters[tile * CSTRIDE], 1,
                               __ATOMIC_RELAXED, __HIP_MEMORY_SCOPE_AGENT);
        while (__hip_atomic_load(&counters[tile * CSTRIDE],
                                 __ATOMIC_RELAXED, __HIP_MEMORY_SCOPE_AGENT) < D)
            __builtin_amdgcn_s_sleep(2);
    }
    __syncthreads();   // (3)

    // ---- tail MLP: this block handles rows d*4 .. d*4+3; wave w<4 -> one row ----
    if (w < 4) {
        int b = b0 + d * 4 + w;
        if (b < B) {
            int c = lane & 31, dg = lane >> 5;   // dg in {0,1}
            float s = 0.f;
#pragma unroll
            for (int i = 0; i < 4; ++i)
                s += __hip_atomic_load(&part[((size_t)b * D + (dg + 2 * i)) * SC + c],
                                       __ATOMIC_RELAXED, __HIP_MEMORY_SCOPE_AGENT);
            s += __shfl_xor(s, 32);
            if (lane < 32) {
                float zz = s + clb_s[c];
#pragma unroll
                for (int a = 0; a < ANT; ++a)
                    zz = fmaf(noise[(b * SC + c) * ANT + a], am_s[c * ANT + a], zz);
                z_s[w][c] = fmaxf(zz, 0.f);
            }
            for (int o = lane; o < 98; o += 64) {
                float s3 = W_lds[OB3 + o];
#pragma unroll
                for (int j = 0; j < SC; ++j) s3 = fmaf(z_s[w][j], W_lds[OW3 + j * 98 + o], s3);
                z3_s[w][o] = fmaxf(s3, 0.f);
            }
            if (lane < 49) {
                float s4 = W_lds[OB4 + lane];
                for (int j = 0; j < 98; ++j) s4 = fmaf(z3_s[w][j], W_lds[OW4 + j * 49 + lane], s4);
                z4_s[w][lane] = fmaxf(s4, 0.f);
            }
            float v = -INFINITY;
            if (lane < 10) {
                float so = W_lds[OBO + lane];
                for (int j = 0; j < 49; ++j) so = fmaf(z4_s[w][j], W_lds[OWO + j * 10 + lane], so);
                v = so;
            }
            float mx = v;
#pragma unroll
            for (int off = 8; off >= 1; off >>= 1) mx = fmaxf(mx, __shfl_xor(mx, off, 16));
            float e = (lane < 10) ? expf(v - mx) : 0.f;
            float ssum = e;
#pragma unroll
            for (int off = 8; off >= 1; off >>= 1) ssum += __shfl_xor(ssum, off, 16);
            if (lane < 10) out[b * 10 + lane] = v - mx - logf(ssum);
        }
    }
}

// ---------------------------------------------------------------------------
extern "C" void kernel_launch(void* const* d_in, const int* in_sizes, int n_in,
                              void* d_out, int out_size, void* d_ws, size_t ws_size,
                              hipStream_t stream) {
    const float* x      = (const float*)d_in[0];
    const float* noise  = (const float*)d_in[1];
    const float* sub_w  = (const float*)d_in[2];
    const float* sub_b  = (const float*)d_in[3];
    const float* ln_g   = (const float*)d_in[4];
    const float* ln_b   = (const float*)d_in[5];
    const float* cut_w  = (const float*)d_in[6];
    const float* cut_b  = (const float*)d_in[7];
    const float* b_mat  = (const float*)d_in[8];
    const float* h_mat  = (const float*)d_in[9];
    const float* a_mat  = (const float*)d_in[10];
    const float* clb    = (const float*)d_in[11];
    const float* fc3_w  = (const float*)d_in[12];
    const float* fc3_b  = (const float*)d_in[13];
    const float* fc4_w  = (const float*)d_in[14];
    const float* fc4_b  = (const float*)d_in[15];
    const float* out_w  = (const float*)d_in[16];
    const float* out_b  = (const float*)d_in[17];
    const int*   k_idx  = (const int*)d_in[18];
    float* out = (float*)d_out;

    char* ws = (char*)d_ws;
    float* part            = (float*)ws;                          // 1,024,000 B [b][d][c]
    unsigned short* sub_wT = (unsigned short*)(ws + (1 << 20));   // 1,048,576 B
    unsigned short* cut_wT = (unsigned short*)(ws + (2 << 20));   //   262,144 B
    float* gw_part         = (float*)(ws + (2 << 20) + 262144);   //     4,096 B
    float* bw_part         = (float*)(ws + (2 << 20) + 266240);   //     4,096 B
    float* coef            = (float*)(ws + (2 << 20) + 270336);   //     1,024 B
    int* counters          = (int*)(ws + (2 << 20) + 271872);     //     4,096 B

    k_prep<<<160, 256, 0, stream>>>(sub_w, cut_w, ln_g, ln_b, cut_b, b_mat,
                                    h_mat, a_mat, k_idx, sub_wT, cut_wT,
                                    gw_part, bw_part, coef, counters);
    k_all<<<D * NTILE, 512, 0, stream>>>(x, sub_wT, sub_b, cut_wT, gw_part,
                                         bw_part, coef, noise, clb, a_mat,
                                         fc3_w, fc3_b, fc4_w, fc4_b, out_w,
                                         out_b, part, counters, out);
}